// Round 3
// baseline (40225.940 us; speedup 1.0000x reference)
//
#include <hip/hip_runtime.h>
#include <hip/hip_cooperative_groups.h>

// Problem constants (fixed by the reference)
#define BATCH 256
#define TLEN  1000
#define HDIM  512

// k-split design
#define S     4                 // k-split ways (blocks per group)
#define G     4                 // batches per group
#define KS    (HDIM / S)        // 128 k-rows (== output cols) per slice
#define NGRP  (BATCH / G)       // 64 groups

// Workspace layout (floats)
#define AZ_OFF   0
#define AZ_SZ    (NGRP * S * G * HDIM)        // 524288
#define AR_OFF   (AZ_OFF + AZ_SZ)
#define AR_SZ    AZ_SZ
#define AH_OFF   (AR_OFF + AR_SZ)
#define AH_SZ    AZ_SZ
#define KP_OFF   (AH_OFF + AH_SZ)
#define KP_SZ    (NGRP * S * G)               // 1024
#define CNT_OFF  (KP_OFF + KP_SZ)             // unsigned counters, NGRP*2
#define WS_NEEDED_BYTES ((size_t)(CNT_OFF + NGRP * 2) * 4)

// 4-block group barrier: monotonic counter, release/acquire via __threadfence.
// __syncthreads before arrive drains every thread's stores (compiler emits
// s_waitcnt vmcnt(0) before s_barrier); tid0's __threadfence (agent release)
// makes them visible at the coherence point; acquire fence after the spin
// invalidates the CU L1 (shared by the whole block) so gather reads can't hit
// stale lines from the previous step.
#define GROUP_BARRIER(CIDX, TARGET) do {                                          \
    __syncthreads();                                                              \
    if (tid == 0) {                                                               \
        __threadfence();                                                          \
        __hip_atomic_fetch_add(&CNT[(grp << 1) + (CIDX)], 1u,                     \
                               __ATOMIC_RELAXED, __HIP_MEMORY_SCOPE_AGENT);       \
        while (__hip_atomic_load(&CNT[(grp << 1) + (CIDX)],                       \
                                 __ATOMIC_RELAXED, __HIP_MEMORY_SCOPE_AGENT)      \
               < (TARGET)) {}                                                     \
        __threadfence();                                                          \
    }                                                                             \
    __syncthreads();                                                              \
} while (0)

// Block (grp, sl): batches [grp*4, grp*4+4), k-slice / col-slice
// [sl*128, sl*128+128). Each weight element is loaded ONCE per group (not once
// per CU-batch) -> per-CU weight traffic 3.15 MB -> 787 KB per step.
// h and h*r for the slice stay block-local (k-range == col-range); only the
// az/ar/ah partials cross blocks (24.6 KB/block/step).
__launch_bounds__(512, 1)
__global__ void mc_gru_ksplit_kernel(
    const float* __restrict__ inputs,  // (B, T)
    const float* __restrict__ St,      // (B)
    const float* __restrict__ Mass,    // (B)
    const float* __restrict__ Wz,      // (513, 512)
    const float* __restrict__ bz,
    const float* __restrict__ Wr,      // (513, 512)
    const float* __restrict__ br,
    const float* __restrict__ Wh,      // (515, 512)
    const float* __restrict__ bh,
    const float* __restrict__ Wk,      // (513)
    const float* __restrict__ bk,      // (1)
    float* __restrict__ out,           // (B, T, H)
    float* __restrict__ AZ,            // [NGRP][S src][G][HDIM]
    float* __restrict__ AR,
    float* __restrict__ AH,
    float* __restrict__ KP,            // [NGRP][S src][G]
    unsigned int* __restrict__ CNT)    // [NGRP][2] (memset to 0 by launcher)
{
    __shared__ float x_l[G][TLEN];     // 16 KB: input rows for the 4 batches
    __shared__ float h_l[G][KS];       // own slice of h_{t-1}
    __shared__ float hr_l[G][KS];      // own slice of h*r
    __shared__ float k_lds[G];         // k carry per batch
    __shared__ float kw_l[8];          // per-wave partials of h_new . Wk

    const int tid = threadIdx.x;
    const int blk = blockIdx.x;
    const int grp = blk & (NGRP - 1);  // 0..63  (members blk = grp + 64j share
    const int sl  = blk >> 6;          // 0..3    blk%8 -> same XCD heuristic)
    const int klo = sl * KS;

    // gather-role cell: batch g2 (of the group), own-slice column c2
    const int g2 = tid >> 7;           // 0..3
    const int cl = tid & 127;          // local col/k index
    const int c2 = klo + cl;

    // ---- one-time staging ----
    for (int g = 0; g < G; ++g)
        for (int idx = tid; idx < TLEN; idx += 512)
            x_l[g][idx] = inputs[(grp * G + g) * TLEN + idx];
    h_l[g2][cl] = 0.0f;                // exactly covers [G][KS]
    if (tid < G) k_lds[tid] = 0.0f;

    // gather-role constants (column c2, batch g2)
    const float wz0g   = Wz[c2];
    const float wr0g   = Wr[c2];
    const float wh0g   = Wh[c2];
    const float wh513g = Wh[513 * HDIM + c2];
    const float wh514g = Wh[514 * HDIM + c2];
    const float bzg    = bz[c2];
    const float brg    = br[c2];
    const float bhg    = bh[c2];
    const float wkg    = Wk[c2];
    const float wk512  = Wk[512];
    const float bk0    = bk[0];
    const float stg    = St[grp * G + g2];
    const float massg  = Mass[grp * G + g2];

    // phase-A/B role: column tid, k-rows [klo, klo+KS)
    const float* __restrict__ WzA = Wz + (size_t)(1 + klo) * HDIM + tid;
    const float* __restrict__ WrA = Wr + (size_t)(1 + klo) * HDIM + tid;
    const float* __restrict__ WhA = Wh + (size_t)(1 + klo) * HDIM + tid;

    // publish/gather pointers
    float* __restrict__ azp = AZ + ((size_t)(grp * S + sl) * G) * HDIM + tid;
    float* __restrict__ arp = AR + ((size_t)(grp * S + sl) * G) * HDIM + tid;
    float* __restrict__ ahp = AH + ((size_t)(grp * S + sl) * G) * HDIM + tid;
    const float* __restrict__ azg = AZ + (size_t)grp * S * G * HDIM + g2 * HDIM + c2;
    const float* __restrict__ arg_ = AR + (size_t)grp * S * G * HDIM + g2 * HDIM + c2;
    const float* __restrict__ ahg = AH + (size_t)grp * S * G * HDIM + g2 * HDIM + c2;

    __syncthreads();                   // staging + h_l init visible in-block

    for (int t = 0; t < TLEN; ++t) {
        // ---------- (A) az/ar partials over own k-slice, all 512 cols ----------
        float az[G] = {0.f, 0.f, 0.f, 0.f};
        float ar[G] = {0.f, 0.f, 0.f, 0.f};
        {
            const float4* h40 = (const float4*)&h_l[0][0];
            const float4* h41 = (const float4*)&h_l[1][0];
            const float4* h42 = (const float4*)&h_l[2][0];
            const float4* h43 = (const float4*)&h_l[3][0];
            #pragma unroll 4
            for (int kq = 0; kq < KS / 4; ++kq) {
                const float4 h0 = h40[kq];    // uniform LDS reads (broadcast)
                const float4 h1 = h41[kq];
                const float4 h2 = h42[kq];
                const float4 h3 = h43[kq];
                #pragma unroll
                for (int kk = 0; kk < 4; ++kk) {
                    const float wzv = WzA[(4 * kq + kk) * HDIM];
                    const float wrv = WrA[(4 * kq + kk) * HDIM];
                    const float h0v = ((const float*)&h0)[kk];
                    const float h1v = ((const float*)&h1)[kk];
                    const float h2v = ((const float*)&h2)[kk];
                    const float h3v = ((const float*)&h3)[kk];
                    az[0] += h0v * wzv;  ar[0] += h0v * wrv;
                    az[1] += h1v * wzv;  ar[1] += h1v * wrv;
                    az[2] += h2v * wzv;  ar[2] += h2v * wrv;
                    az[3] += h3v * wzv;  ar[3] += h3v * wrv;
                }
            }
        }
        #pragma unroll
        for (int g = 0; g < G; ++g) { azp[g * HDIM] = az[g]; arp[g * HDIM] = ar[g]; }

        GROUP_BARRIER(0, (unsigned)(S * (t + 1)));

        // ---------- (B) gather z,r for own cell; hr; k carry; ah partials ----------
        float azs = 0.f, ars = 0.f;
        #pragma unroll
        for (int src = 0; src < S; ++src) {
            azs += azg[src * G * HDIM];
            ars += arg_[src * G * HDIM];
        }
        const float x2 = x_l[g2][t];
        const float z  = 1.0f / (1.0f + __expf(-(azs + x2 * wz0g + bzg)));
        const float r  = 1.0f / (1.0f + __expf(-(ars + x2 * wr0g + brg)));
        const float hv = h_l[g2][cl];
        hr_l[g2][cl] = hv * r;

        // k_{t-1} gather (published at (C) of step t-1)
        if (tid < G && t > 0) {
            const float* kpp = KP + (size_t)grp * S * G + tid;
            float ks = 0.f;
            #pragma unroll
            for (int src = 0; src < S; ++src) ks += kpp[src * G];
            k_lds[tid] = 1.0f / (1.0f + __expf(-(ks + wk512 * k_lds[tid] + bk0)));
        }
        __syncthreads();               // hr_l + k_lds ready

        float ah[G] = {0.f, 0.f, 0.f, 0.f};
        {
            const float4* r40 = (const float4*)&hr_l[0][0];
            const float4* r41 = (const float4*)&hr_l[1][0];
            const float4* r42 = (const float4*)&hr_l[2][0];
            const float4* r43 = (const float4*)&hr_l[3][0];
            #pragma unroll 4
            for (int kq = 0; kq < KS / 4; ++kq) {
                const float4 h0 = r40[kq];
                const float4 h1 = r41[kq];
                const float4 h2 = r42[kq];
                const float4 h3 = r43[kq];
                #pragma unroll
                for (int kk = 0; kk < 4; ++kk) {
                    const float whv = WhA[(4 * kq + kk) * HDIM];
                    ah[0] += ((const float*)&h0)[kk] * whv;
                    ah[1] += ((const float*)&h1)[kk] * whv;
                    ah[2] += ((const float*)&h2)[kk] * whv;
                    ah[3] += ((const float*)&h3)[kk] * whv;
                }
            }
        }
        #pragma unroll
        for (int g = 0; g < G; ++g) ahp[g * HDIM] = ah[g];

        GROUP_BARRIER(1, (unsigned)(S * (t + 1)));

        // ---------- (C) gather ah; state update for own cell ----------
        float ahs = 0.f;
        #pragma unroll
        for (int src = 0; src < S; ++src) ahs += ahg[src * G * HDIM];
        const float kg  = k_lds[g2];
        const float pre = ahs + x2 * wh0g + (stg * kg) * wh513g + massg * wh514g + bhg;
        const float e   = __expf(-2.0f * pre);
        const float ht  = (1.0f - e) / (1.0f + e);       // tanh
        const float hn  = (1.0f - z) * hv + z * ht;

        __builtin_nontemporal_store(hn, &out[((size_t)(grp * G + g2) * TLEN + t) * HDIM + c2]);
        h_l[g2][cl] = hn;

        // k partial: own-slice dot with Wk, reduced per batch (2 waves each)
        float kc = hn * wkg;
        kc += __shfl_xor(kc, 1);
        kc += __shfl_xor(kc, 2);
        kc += __shfl_xor(kc, 4);
        kc += __shfl_xor(kc, 8);
        kc += __shfl_xor(kc, 16);
        kc += __shfl_xor(kc, 32);
        if ((tid & 63) == 0) kw_l[tid >> 6] = kc;
        __syncthreads();               // h_l + kw_l ready
        if (tid < G)
            KP[(size_t)(grp * S + sl) * G + tid] = kw_l[2 * tid] + kw_l[2 * tid + 1];
        // KP visibility to other blocks is covered by barrier 0 of step t+1.
    }
}

// ---------------- fallback: round-1 kernel (no workspace needed) ----------------
__launch_bounds__(512, 1)
__global__ void mc_gru_batch_kernel(
    const float* __restrict__ inputs, const float* __restrict__ St,
    const float* __restrict__ Mass, const float* __restrict__ Wz,
    const float* __restrict__ bz, const float* __restrict__ Wr,
    const float* __restrict__ br, const float* __restrict__ Wh,
    const float* __restrict__ bh, const float* __restrict__ Wk,
    const float* __restrict__ bk, float* __restrict__ out)
{
    __shared__ float x_l[TLEN];
    __shared__ float h_l[HDIM];
    __shared__ float hr_l[HDIM];
    __shared__ float kw_l[8];

    const int c = threadIdx.x;
    const int b = blockIdx.x;

    for (int idx = c; idx < TLEN; idx += 512) x_l[idx] = inputs[b * TLEN + idx];
    h_l[c] = 0.0f;

    const float wz0 = Wz[c], wr0 = Wr[c], wh0 = Wh[c];
    const float wh513 = Wh[513 * HDIM + c], wh514 = Wh[514 * HDIM + c];
    const float bzc = bz[c], brc = br[c], bhc = bh[c], wkc = Wk[c];
    const float wk512 = Wk[512], bk0 = bk[0];
    const float st = St[b], mass = Mass[b];

    const float* __restrict__ Wz1 = Wz + HDIM + c;
    const float* __restrict__ Wr1 = Wr + HDIM + c;
    const float* __restrict__ Wh1 = Wh + HDIM + c;

    float h_reg = 0.0f, k_reg = 0.0f;
    __syncthreads();

    for (int t = 0; t < TLEN; ++t) {
        const float x = x_l[t];
        float az = x * wz0, ar = x * wr0;
        const float4* h4 = (const float4*)h_l;
        #pragma unroll 4
        for (int k4 = 0; k4 < HDIM / 4; ++k4) {
            const float4 hv = h4[k4];
            const int k = 4 * k4;
            az += hv.x * Wz1[(k + 0) * HDIM] + hv.y * Wz1[(k + 1) * HDIM]
                + hv.z * Wz1[(k + 2) * HDIM] + hv.w * Wz1[(k + 3) * HDIM];
            ar += hv.x * Wr1[(k + 0) * HDIM] + hv.y * Wr1[(k + 1) * HDIM]
                + hv.z * Wr1[(k + 2) * HDIM] + hv.w * Wr1[(k + 3) * HDIM];
        }
        const float z = 1.0f / (1.0f + __expf(-(az + bzc)));
        const float r = 1.0f / (1.0f + __expf(-(ar + brc)));
        hr_l[c] = h_reg * r;
        __syncthreads();

        float ah = x * wh0 + (st * k_reg) * wh513 + mass * wh514 + bhc;
        const float4* hr4 = (const float4*)hr_l;
        #pragma unroll 4
        for (int k4 = 0; k4 < HDIM / 4; ++k4) {
            const float4 hv = hr4[k4];
            const int k = 4 * k4;
            ah += hv.x * Wh1[(k + 0) * HDIM] + hv.y * Wh1[(k + 1) * HDIM]
                + hv.z * Wh1[(k + 2) * HDIM] + hv.w * Wh1[(k + 3) * HDIM];
        }
        const float e  = __expf(-2.0f * ah);
        const float ht = (1.0f - e) / (1.0f + e);
        const float hn = (1.0f - z) * h_reg + z * ht;
        h_reg = hn;

        __builtin_nontemporal_store(hn, &out[(b * TLEN + t) * HDIM + c]);
        h_l[c] = hn;

        float kc = hn * wkc;
        kc += __shfl_xor(kc, 1);
        kc += __shfl_xor(kc, 2);
        kc += __shfl_xor(kc, 4);
        kc += __shfl_xor(kc, 8);
        kc += __shfl_xor(kc, 16);
        kc += __shfl_xor(kc, 32);
        if ((c & 63) == 0) kw_l[c >> 6] = kc;
        __syncthreads();

        const float ksum = kw_l[0] + kw_l[1] + kw_l[2] + kw_l[3]
                         + kw_l[4] + kw_l[5] + kw_l[6] + kw_l[7];
        k_reg = 1.0f / (1.0f + __expf(-(ksum + wk512 * k_reg + bk0)));
    }
}

extern "C" void kernel_launch(void* const* d_in, const int* in_sizes, int n_in,
                              void* d_out, int out_size, void* d_ws, size_t ws_size,
                              hipStream_t stream) {
    (void)in_sizes; (void)n_in; (void)out_size;

    const float* inputs = (const float*)d_in[0];
    const float* St     = (const float*)d_in[1];
    const float* Mass   = (const float*)d_in[2];
    const float* Wz     = (const float*)d_in[3];
    const float* bz     = (const float*)d_in[4];
    const float* Wr     = (const float*)d_in[5];
    const float* br     = (const float*)d_in[6];
    const float* Wh     = (const float*)d_in[7];
    const float* bh     = (const float*)d_in[8];
    const float* Wk     = (const float*)d_in[9];
    const float* bk     = (const float*)d_in[10];
    float* out = (float*)d_out;

    if (ws_size >= WS_NEEDED_BYTES) {
        float* ws = (float*)d_ws;
        float* AZ = ws + AZ_OFF;
        float* AR = ws + AR_OFF;
        float* AH = ws + AH_OFF;
        float* KP = ws + KP_OFF;
        unsigned int* CNT = (unsigned int*)(ws + CNT_OFF);

        // d_ws is poisoned before each launch -> barrier counters must start 0
        hipMemsetAsync(CNT, 0, NGRP * 2 * sizeof(unsigned int), stream);

        void* args[] = {
            (void*)&inputs, (void*)&St, (void*)&Mass,
            (void*)&Wz, (void*)&bz, (void*)&Wr, (void*)&br,
            (void*)&Wh, (void*)&bh, (void*)&Wk, (void*)&bk,
            (void*)&out, (void*)&AZ, (void*)&AR, (void*)&AH,
            (void*)&KP, (void*)&CNT
        };
        hipLaunchCooperativeKernel((const void*)mc_gru_ksplit_kernel,
                                   dim3(BATCH), dim3(512), args, 0, stream);
    } else {
        // workspace too small for the k-split exchange buffers: known-good path
        hipLaunchKernelGGL(mc_gru_batch_kernel, dim3(BATCH), dim3(512), 0, stream,
                           inputs, St, Mass, Wz, bz, Wr, br, Wh, bh, Wk, bk, out);
    }
}

// Round 4
// 26020.724 us; speedup vs baseline: 1.5459x; 1.5459x over previous
//
#include <hip/hip_runtime.h>

// Problem constants (fixed by the reference)
#define BATCH 256
#define TLEN  1000
#define HDIM  512
#define HALF  256   // k-rows per half (2-way in-block k-split)

// One block per batch, 1024 threads = 16 waves/CU (4/SIMD) for latency hiding.
// Thread (half, c): half = tid>>9 owns k-rows [half*256, half*256+256) of
// column c = tid&511. All state (h, h*r, k, partial sums) is block-local:
// zero cross-block traffic, zero device-scope fences (round-3 lesson: agent
// fences destroy L2 weight residency). Weights stream L2->L1 at 3.15 MB/CU/step;
// 16 waves keep enough loads in flight to approach the ~144 GB/s/CU ceiling.
__launch_bounds__(1024, 4)
__global__ void mc_gru_k2_kernel(
    const float* __restrict__ inputs,  // (B, T)  [IN==1]
    const float* __restrict__ St,      // (B)
    const float* __restrict__ Mass,    // (B)
    const float* __restrict__ Wz,      // (513, 512) row-major
    const float* __restrict__ bz,      // (512)
    const float* __restrict__ Wr,      // (513, 512)
    const float* __restrict__ br,      // (512)
    const float* __restrict__ Wh,      // (515, 512)
    const float* __restrict__ bh,      // (512)
    const float* __restrict__ Wk,      // (513)
    const float* __restrict__ bk,      // (1)
    float* __restrict__ out)           // (B, T, H)
{
    __shared__ float x_l[TLEN];        // input row for this batch (4 KB)
    __shared__ float h_l[HDIM];        // h_{t-1}
    __shared__ float hr_l[HDIM];       // h * r
    __shared__ float az_s[2 * HDIM];   // per-(half,col) partial of comb@Wz
    __shared__ float ar_s[2 * HDIM];   // per-(half,col) partial of comb@Wr
    __shared__ float ah_s[2 * HDIM];   // per-(half,col) partial of h_in@Wh
    __shared__ float kw_l[8];          // per-wave partials of h_new . Wk

    const int tid  = threadIdx.x;
    const int b    = blockIdx.x;
    const int c    = tid & (HDIM - 1); // column 0..511
    const int half = tid >> 9;         // k-half 0/1 (wave-uniform)
    const int klo  = half * HALF;

    // one-time staging
    for (int idx = tid; idx < TLEN; idx += 1024) x_l[idx] = inputs[b * TLEN + idx];
    if (tid < HDIM) h_l[tid] = 0.0f;

    // time-invariant per-column scalars
    const float wz0   = Wz[c];
    const float wr0   = Wr[c];
    const float wh0   = Wh[c];
    const float wh513 = Wh[513 * HDIM + c];
    const float wh514 = Wh[514 * HDIM + c];
    const float bzc   = bz[c];
    const float brc   = br[c];
    const float bhc   = bh[c];
    const float wkc   = Wk[c];
    const float wk512 = Wk[512];
    const float bk0   = bk[0];
    const float st    = St[b];
    const float mass  = Mass[b];

    // weight bases: own column, own k-half, rows 1..512 of W*
    const float* __restrict__ WzH = Wz + (size_t)(1 + klo) * HDIM + c;
    const float* __restrict__ WrH = Wr + (size_t)(1 + klo) * HDIM + c;
    const float* __restrict__ WhH = Wh + (size_t)(1 + klo) * HDIM + c;

    float k_reg = 0.0f;                // k carry (consistent across all threads)
    __syncthreads();

    for (int t = 0; t < TLEN; ++t) {
        const float x = x_l[t];

        // ---------- phase A: az/ar partial over own k-half ----------
        float azp = 0.0f, arp = 0.0f;
        {
            const float4* h4 = (const float4*)&h_l[klo];   // uniform (broadcast)
            #pragma unroll 4
            for (int kq = 0; kq < HALF / 4; ++kq) {
                const float4 hv = h4[kq];
                const int k = 4 * kq;
                azp += hv.x * WzH[(k + 0) * HDIM] + hv.y * WzH[(k + 1) * HDIM]
                     + hv.z * WzH[(k + 2) * HDIM] + hv.w * WzH[(k + 3) * HDIM];
                arp += hv.x * WrH[(k + 0) * HDIM] + hv.y * WrH[(k + 1) * HDIM]
                     + hv.z * WrH[(k + 2) * HDIM] + hv.w * WrH[(k + 3) * HDIM];
            }
        }
        az_s[tid] = azp;
        ar_s[tid] = arp;
        __syncthreads();                           // S1: partials ready

        // gates (computed redundantly by both halves — wave-uniform, no extra time)
        const float z = 1.0f / (1.0f + __expf(-(az_s[c] + az_s[HDIM + c] + x * wz0 + bzc)));
        const float r = 1.0f / (1.0f + __expf(-(ar_s[c] + ar_s[HDIM + c] + x * wr0 + brc)));
        const float hvv = h_l[c];
        if (half == 0) hr_l[c] = hvv * r;
        __syncthreads();                           // S2: hr_l ready

        // ---------- phase B: ah partial over own k-half ----------
        float ahp = 0.0f;
        {
            const float4* hr4 = (const float4*)&hr_l[klo];
            #pragma unroll 4
            for (int kq = 0; kq < HALF / 4; ++kq) {
                const float4 hv = hr4[kq];
                const int k = 4 * kq;
                ahp += hv.x * WhH[(k + 0) * HDIM] + hv.y * WhH[(k + 1) * HDIM]
                     + hv.z * WhH[(k + 2) * HDIM] + hv.w * WhH[(k + 3) * HDIM];
            }
        }
        ah_s[tid] = ahp;
        __syncthreads();                           // S3: ah partials ready

        // state update (redundant across halves; only half 0 stores)
        const float pre = ah_s[c] + ah_s[HDIM + c] + x * wh0
                        + (st * k_reg) * wh513 + mass * wh514 + bhc;
        const float e  = __expf(-2.0f * pre);
        const float ht = (1.0f - e) / (1.0f + e);  // tanh
        const float hn = (1.0f - z) * hvv + z * ht;

        if (half == 0) {
            // non-temporal: keep the output stream from evicting L2-resident weights
            __builtin_nontemporal_store(hn, &out[((size_t)b * TLEN + t) * HDIM + c]);
            h_l[c] = hn;
            // k partial: h_new . Wk, wave shuffle reduce (waves 0..7)
            float kc = hn * wkc;
            kc += __shfl_xor(kc, 1);
            kc += __shfl_xor(kc, 2);
            kc += __shfl_xor(kc, 4);
            kc += __shfl_xor(kc, 8);
            kc += __shfl_xor(kc, 16);
            kc += __shfl_xor(kc, 32);
            if ((tid & 63) == 0) kw_l[tid >> 6] = kc;
        }
        __syncthreads();                           // S4: h_l + kw_l published

        const float ksum = kw_l[0] + kw_l[1] + kw_l[2] + kw_l[3]
                         + kw_l[4] + kw_l[5] + kw_l[6] + kw_l[7];
        k_reg = 1.0f / (1.0f + __expf(-(ksum + wk512 * k_reg + bk0)));
    }
}

extern "C" void kernel_launch(void* const* d_in, const int* in_sizes, int n_in,
                              void* d_out, int out_size, void* d_ws, size_t ws_size,
                              hipStream_t stream) {
    (void)in_sizes; (void)n_in; (void)out_size; (void)d_ws; (void)ws_size;

    const float* inputs = (const float*)d_in[0];
    const float* St     = (const float*)d_in[1];
    const float* Mass   = (const float*)d_in[2];
    const float* Wz     = (const float*)d_in[3];
    const float* bz     = (const float*)d_in[4];
    const float* Wr     = (const float*)d_in[5];
    const float* br     = (const float*)d_in[6];
    const float* Wh     = (const float*)d_in[7];
    const float* bh     = (const float*)d_in[8];
    const float* Wk     = (const float*)d_in[9];
    const float* bk     = (const float*)d_in[10];
    float* out = (float*)d_out;

    hipLaunchKernelGGL(mc_gru_k2_kernel, dim3(BATCH), dim3(1024), 0, stream,
                       inputs, St, Mass, Wz, bz, Wr, br, Wh, bh, Wk, bk, out);
}

// Round 5
// 17561.128 us; speedup vs baseline: 2.2906x; 1.4817x over previous
//
#include <hip/hip_runtime.h>
#include <hip/hip_fp16.h>

// Problem constants (fixed by the reference)
#define BATCH 256
#define TLEN  1000
#define HDIM  512
#define HALF  256   // k-rows per half (2-way in-block k-split)
#define NQ    128   // 4-row k-groups (512/4)

// Packed fp16 weight workspace layout (in d_ws):
//   ZR[q][c] uint4: {h2(Wz r,r+1), h2(Wr r,r+1), h2(Wz r+2,r+3), h2(Wr r+2,r+3)}, r=1+4q
//   WH[q][c] uint2: {h2(Wh r,r+1), h2(Wh r+2,r+3)}
#define ZR_ELEMS   (NQ * HDIM)                       // 65536 uint4 = 1 MB
#define WH_OFF_B   ((size_t)ZR_ELEMS * 16)
#define WS16_BYTES (WH_OFF_B + (size_t)ZR_ELEMS * 8) // 1.573 MB

__device__ __forceinline__ unsigned int f2h2(float a, float b) {
    __half2 h = __halves2half2(__float2half_rn(a), __float2half_rn(b));
    return __builtin_bit_cast(unsigned int, h);
}
__device__ __forceinline__ float2 h2f(unsigned int u) {
    return __half22float2(__builtin_bit_cast(__half2, u));
}

// per-launch weight conversion: fp32 (513/515 x 512) -> packed fp16 (d_ws is
// poisoned before every launch, so this must re-run each time; ~10 us)
__global__ void convert_weights_kernel(
    const float* __restrict__ Wz, const float* __restrict__ Wr,
    const float* __restrict__ Wh, uint4* __restrict__ ZR, uint2* __restrict__ WH)
{
    const int idx = blockIdx.x * 256 + threadIdx.x;   // 0..65535
    const int q = idx >> 9;                           // 0..127
    const int c = idx & (HDIM - 1);
    const size_t r0 = (size_t)(1 + 4 * q) * HDIM + c; // W row 1+4q, own column
    uint4 z;
    z.x = f2h2(Wz[r0],            Wz[r0 + HDIM]);
    z.y = f2h2(Wr[r0],            Wr[r0 + HDIM]);
    z.z = f2h2(Wz[r0 + 2 * HDIM], Wz[r0 + 3 * HDIM]);
    z.w = f2h2(Wr[r0 + 2 * HDIM], Wr[r0 + 3 * HDIM]);
    ZR[idx] = z;
    uint2 h;
    h.x = f2h2(Wh[r0],            Wh[r0 + HDIM]);
    h.y = f2h2(Wh[r0 + 2 * HDIM], Wh[r0 + 3 * HDIM]);
    WH[idx] = h;
}

// One block per batch, 1024 threads (16 waves/CU). Thread (half, c) owns
// k-rows [half*256, half*256+256) of column c. All state block-local (round-3
// lesson: cross-CU fences destroy L2 residency). fp16 weights halve the
// aggregate L2 stream (was 82% of the 34.5 TB/s L2 ceiling at fp32 -> round-4's
// wall). h and all accumulation stay fp32; only weights are rounded.
__launch_bounds__(1024, 4)
__global__ void mc_gru_k2_h16_kernel(
    const float* __restrict__ inputs,  // (B, T)  [IN==1]
    const float* __restrict__ St,      // (B)
    const float* __restrict__ Mass,    // (B)
    const float* __restrict__ Wz,      // (513, 512) fp32 (row0 + scalars only)
    const float* __restrict__ bz,      // (512)
    const float* __restrict__ Wr,      // (513, 512)
    const float* __restrict__ br,      // (512)
    const float* __restrict__ Wh,      // (515, 512)
    const float* __restrict__ bh,      // (512)
    const float* __restrict__ Wk,      // (513)
    const float* __restrict__ bk,      // (1)
    const uint4* __restrict__ ZR,      // packed fp16 Wz|Wr
    const uint2* __restrict__ WH,      // packed fp16 Wh
    float* __restrict__ out)           // (B, T, H)
{
    __shared__ float x_l[TLEN];        // input row for this batch (4 KB)
    __shared__ float h_l[HDIM];        // h_{t-1}
    __shared__ float hr_l[HDIM];       // h * r
    __shared__ float az_s[2 * HDIM];   // per-(half,col) partials
    __shared__ float ar_s[2 * HDIM];
    __shared__ float ah_s[2 * HDIM];
    __shared__ float kw_l[8];          // per-wave partials of h_new . Wk

    const int tid  = threadIdx.x;
    const int b    = blockIdx.x;
    const int c    = tid & (HDIM - 1); // column 0..511
    const int half = tid >> 9;         // k-half 0/1 (wave-uniform)
    const int klo  = half * HALF;

    for (int idx = tid; idx < TLEN; idx += 1024) x_l[idx] = inputs[b * TLEN + idx];
    if (tid < HDIM) h_l[tid] = 0.0f;

    // time-invariant per-column scalars (fp32, from the original arrays)
    const float wz0   = Wz[c];
    const float wr0   = Wr[c];
    const float wh0   = Wh[c];
    const float wh513 = Wh[513 * HDIM + c];
    const float wh514 = Wh[514 * HDIM + c];
    const float bzc   = bz[c];
    const float brc   = br[c];
    const float bhc   = bh[c];
    const float wkc   = Wk[c];
    const float wk512 = Wk[512];
    const float bk0   = bk[0];
    const float st    = St[b];
    const float mass  = Mass[b];

    // packed-weight bases: own column, own k-half (q = half*64 + qi)
    const uint4* __restrict__ zrp = ZR + (size_t)(half * 64) * HDIM + c;
    const uint2* __restrict__ whp = WH + (size_t)(half * 64) * HDIM + c;

    float k_reg = 0.0f;                // k carry (uniform across block)
    __syncthreads();

    for (int t = 0; t < TLEN; ++t) {
        const float x = x_l[t];

        // ---------- phase A: az/ar partial over own k-half ----------
        float azp = 0.0f, arp = 0.0f;
        {
            const float4* h4 = (const float4*)&h_l[klo];   // uniform (broadcast)
            #pragma unroll 4
            for (int qi = 0; qi < HALF / 4; ++qi) {
                const uint4  v  = zrp[(size_t)qi * HDIM];  // 4 k-rows, both gates
                const float4 hv = h4[qi];
                const float2 wz01 = h2f(v.x);
                const float2 wr01 = h2f(v.y);
                const float2 wz23 = h2f(v.z);
                const float2 wr23 = h2f(v.w);
                azp += hv.x * wz01.x + hv.y * wz01.y + hv.z * wz23.x + hv.w * wz23.y;
                arp += hv.x * wr01.x + hv.y * wr01.y + hv.z * wr23.x + hv.w * wr23.y;
            }
        }
        az_s[tid] = azp;
        ar_s[tid] = arp;
        __syncthreads();                           // S1: partials ready

        // gates (computed redundantly by both halves — wave-uniform)
        const float z = 1.0f / (1.0f + __expf(-(az_s[c] + az_s[HDIM + c] + x * wz0 + bzc)));
        const float r = 1.0f / (1.0f + __expf(-(ar_s[c] + ar_s[HDIM + c] + x * wr0 + brc)));
        const float hvv = h_l[c];
        if (half == 0) hr_l[c] = hvv * r;
        __syncthreads();                           // S2: hr_l ready

        // ---------- phase B: ah partial over own k-half ----------
        float ahp = 0.0f;
        {
            const float4* hr4 = (const float4*)&hr_l[klo];
            #pragma unroll 4
            for (int qi = 0; qi < HALF / 4; ++qi) {
                const uint2  v  = whp[(size_t)qi * HDIM];
                const float4 hv = hr4[qi];
                const float2 w01 = h2f(v.x);
                const float2 w23 = h2f(v.y);
                ahp += hv.x * w01.x + hv.y * w01.y + hv.z * w23.x + hv.w * w23.y;
            }
        }
        ah_s[tid] = ahp;
        __syncthreads();                           // S3: ah partials ready

        // state update (redundant across halves; only half 0 stores)
        const float pre = ah_s[c] + ah_s[HDIM + c] + x * wh0
                        + (st * k_reg) * wh513 + mass * wh514 + bhc;
        const float e  = __expf(-2.0f * pre);
        const float ht = (1.0f - e) / (1.0f + e);  // tanh
        const float hn = (1.0f - z) * hvv + z * ht;

        if (half == 0) {
            __builtin_nontemporal_store(hn, &out[((size_t)b * TLEN + t) * HDIM + c]);
            h_l[c] = hn;
            float kc = hn * wkc;                   // h_new . Wk partial
            kc += __shfl_xor(kc, 1);
            kc += __shfl_xor(kc, 2);
            kc += __shfl_xor(kc, 4);
            kc += __shfl_xor(kc, 8);
            kc += __shfl_xor(kc, 16);
            kc += __shfl_xor(kc, 32);
            if ((tid & 63) == 0) kw_l[tid >> 6] = kc;
        }
        __syncthreads();                           // S4: h_l + kw_l published

        const float ksum = kw_l[0] + kw_l[1] + kw_l[2] + kw_l[3]
                         + kw_l[4] + kw_l[5] + kw_l[6] + kw_l[7];
        k_reg = 1.0f / (1.0f + __expf(-(ksum + wk512 * k_reg + bk0)));
    }
}

// ---------------- fallback: round-4 fp32 kernel (no workspace needed) ----------------
__launch_bounds__(1024, 4)
__global__ void mc_gru_k2_kernel(
    const float* __restrict__ inputs, const float* __restrict__ St,
    const float* __restrict__ Mass, const float* __restrict__ Wz,
    const float* __restrict__ bz, const float* __restrict__ Wr,
    const float* __restrict__ br, const float* __restrict__ Wh,
    const float* __restrict__ bh, const float* __restrict__ Wk,
    const float* __restrict__ bk, float* __restrict__ out)
{
    __shared__ float x_l[TLEN];
    __shared__ float h_l[HDIM];
    __shared__ float hr_l[HDIM];
    __shared__ float az_s[2 * HDIM];
    __shared__ float ar_s[2 * HDIM];
    __shared__ float ah_s[2 * HDIM];
    __shared__ float kw_l[8];

    const int tid  = threadIdx.x;
    const int b    = blockIdx.x;
    const int c    = tid & (HDIM - 1);
    const int half = tid >> 9;
    const int klo  = half * HALF;

    for (int idx = tid; idx < TLEN; idx += 1024) x_l[idx] = inputs[b * TLEN + idx];
    if (tid < HDIM) h_l[tid] = 0.0f;

    const float wz0 = Wz[c], wr0 = Wr[c], wh0 = Wh[c];
    const float wh513 = Wh[513 * HDIM + c], wh514 = Wh[514 * HDIM + c];
    const float bzc = bz[c], brc = br[c], bhc = bh[c], wkc = Wk[c];
    const float wk512 = Wk[512], bk0 = bk[0];
    const float st = St[b], mass = Mass[b];

    const float* __restrict__ WzH = Wz + (size_t)(1 + klo) * HDIM + c;
    const float* __restrict__ WrH = Wr + (size_t)(1 + klo) * HDIM + c;
    const float* __restrict__ WhH = Wh + (size_t)(1 + klo) * HDIM + c;

    float k_reg = 0.0f;
    __syncthreads();

    for (int t = 0; t < TLEN; ++t) {
        const float x = x_l[t];
        float azp = 0.0f, arp = 0.0f;
        {
            const float4* h4 = (const float4*)&h_l[klo];
            #pragma unroll 4
            for (int kq = 0; kq < HALF / 4; ++kq) {
                const float4 hv = h4[kq];
                const int k = 4 * kq;
                azp += hv.x * WzH[(k + 0) * HDIM] + hv.y * WzH[(k + 1) * HDIM]
                     + hv.z * WzH[(k + 2) * HDIM] + hv.w * WzH[(k + 3) * HDIM];
                arp += hv.x * WrH[(k + 0) * HDIM] + hv.y * WrH[(k + 1) * HDIM]
                     + hv.z * WrH[(k + 2) * HDIM] + hv.w * WrH[(k + 3) * HDIM];
            }
        }
        az_s[tid] = azp;
        ar_s[tid] = arp;
        __syncthreads();

        const float z = 1.0f / (1.0f + __expf(-(az_s[c] + az_s[HDIM + c] + x * wz0 + bzc)));
        const float r = 1.0f / (1.0f + __expf(-(ar_s[c] + ar_s[HDIM + c] + x * wr0 + brc)));
        const float hvv = h_l[c];
        if (half == 0) hr_l[c] = hvv * r;
        __syncthreads();

        float ahp = 0.0f;
        {
            const float4* hr4 = (const float4*)&hr_l[klo];
            #pragma unroll 4
            for (int kq = 0; kq < HALF / 4; ++kq) {
                const float4 hv = hr4[kq];
                const int k = 4 * kq;
                ahp += hv.x * WhH[(k + 0) * HDIM] + hv.y * WhH[(k + 1) * HDIM]
                     + hv.z * WhH[(k + 2) * HDIM] + hv.w * WhH[(k + 3) * HDIM];
            }
        }
        ah_s[tid] = ahp;
        __syncthreads();

        const float pre = ah_s[c] + ah_s[HDIM + c] + x * wh0
                        + (st * k_reg) * wh513 + mass * wh514 + bhc;
        const float e  = __expf(-2.0f * pre);
        const float ht = (1.0f - e) / (1.0f + e);
        const float hn = (1.0f - z) * hvv + z * ht;

        if (half == 0) {
            __builtin_nontemporal_store(hn, &out[((size_t)b * TLEN + t) * HDIM + c]);
            h_l[c] = hn;
            float kc = hn * wkc;
            kc += __shfl_xor(kc, 1);
            kc += __shfl_xor(kc, 2);
            kc += __shfl_xor(kc, 4);
            kc += __shfl_xor(kc, 8);
            kc += __shfl_xor(kc, 16);
            kc += __shfl_xor(kc, 32);
            if ((tid & 63) == 0) kw_l[tid >> 6] = kc;
        }
        __syncthreads();

        const float ksum = kw_l[0] + kw_l[1] + kw_l[2] + kw_l[3]
                         + kw_l[4] + kw_l[5] + kw_l[6] + kw_l[7];
        k_reg = 1.0f / (1.0f + __expf(-(ksum + wk512 * k_reg + bk0)));
    }
}

extern "C" void kernel_launch(void* const* d_in, const int* in_sizes, int n_in,
                              void* d_out, int out_size, void* d_ws, size_t ws_size,
                              hipStream_t stream) {
    (void)in_sizes; (void)n_in; (void)out_size;

    const float* inputs = (const float*)d_in[0];
    const float* St     = (const float*)d_in[1];
    const float* Mass   = (const float*)d_in[2];
    const float* Wz     = (const float*)d_in[3];
    const float* bz     = (const float*)d_in[4];
    const float* Wr     = (const float*)d_in[5];
    const float* br     = (const float*)d_in[6];
    const float* Wh     = (const float*)d_in[7];
    const float* bh     = (const float*)d_in[8];
    const float* Wk     = (const float*)d_in[9];
    const float* bk     = (const float*)d_in[10];
    float* out = (float*)d_out;

    if (ws_size >= WS16_BYTES) {
        uint4* ZR = (uint4*)d_ws;
        uint2* WH = (uint2*)((char*)d_ws + WH_OFF_B);
        hipLaunchKernelGGL(convert_weights_kernel, dim3(ZR_ELEMS / 256), dim3(256),
                           0, stream, Wz, Wr, Wh, ZR, WH);
        hipLaunchKernelGGL(mc_gru_k2_h16_kernel, dim3(BATCH), dim3(1024), 0, stream,
                           inputs, St, Mass, Wz, bz, Wr, br, Wh, bh, Wk, bk,
                           (const uint4*)ZR, (const uint2*)WH, out);
    } else {
        hipLaunchKernelGGL(mc_gru_k2_kernel, dim3(BATCH), dim3(1024), 0, stream,
                           inputs, St, Mass, Wz, bz, Wr, br, Wh, bh, Wk, bk, out);
    }
}

// Round 6
// 16193.777 us; speedup vs baseline: 2.4840x; 1.0844x over previous
//
#include <hip/hip_runtime.h>
#include <hip/hip_fp16.h>

// Problem constants (fixed by the reference)
#define BATCH 256
#define TLEN  1000
#define HDIM  512
#define HALF  256   // k-rows per half (2-way in-block k-split)
#define NQ    128   // 4-row k-groups (512/4)

// Packed fp16 weight workspace layout (in d_ws):
//   ZR[q][c] uint4: {h2(Wz r,r+1), h2(Wr r,r+1), h2(Wz r+2,r+3), h2(Wr r+2,r+3)}, r=1+4q
//   WH[q][c] uint2: {h2(Wh r,r+1), h2(Wh r+2,r+3)}
#define ZR_ELEMS   (NQ * HDIM)                       // 65536 uint4 = 1 MB
#define WH_OFF_B   ((size_t)ZR_ELEMS * 16)
#define WS16_BYTES (WH_OFF_B + (size_t)ZR_ELEMS * 8) // 1.573 MB

typedef _Float16 f16;
typedef f16 f16x2 __attribute__((ext_vector_type(2)));

__device__ __forceinline__ unsigned int f2h2(float a, float b) {
    __half2 h = __halves2half2(__float2half_rn(a), __float2half_rn(b));
    return __builtin_bit_cast(unsigned int, h);
}

// fp16x2 dot with fp32 accumulate: v_dot2_f32_f16 (one instr, no cvts)
__device__ __forceinline__ float fdot2f(unsigned int a, unsigned int b, float c) {
#if __has_builtin(__builtin_amdgcn_fdot2)
    return __builtin_amdgcn_fdot2(__builtin_bit_cast(f16x2, a),
                                  __builtin_bit_cast(f16x2, b), c, false);
#else
    const f16x2 x = __builtin_bit_cast(f16x2, a);
    const f16x2 y = __builtin_bit_cast(f16x2, b);
    return c + (float)x[0] * (float)y[0] + (float)x[1] * (float)y[1];
#endif
}

// pack two fp32 -> fp16x2 (single v_cvt_pkrtz_f16_f32 where available)
__device__ __forceinline__ unsigned int pack2(float a, float b) {
#if __has_builtin(__builtin_amdgcn_cvt_pkrtz)
    return __builtin_bit_cast(unsigned int, __builtin_amdgcn_cvt_pkrtz(a, b));
#else
    f16x2 v; v[0] = (f16)a; v[1] = (f16)b;
    return __builtin_bit_cast(unsigned int, v);
#endif
}

// per-launch weight conversion (d_ws is poisoned before every launch)
__global__ void convert_weights_kernel(
    const float* __restrict__ Wz, const float* __restrict__ Wr,
    const float* __restrict__ Wh, uint4* __restrict__ ZR, uint2* __restrict__ WH)
{
    const int idx = blockIdx.x * 256 + threadIdx.x;   // 0..65535
    const int q = idx >> 9;                           // 0..127
    const int c = idx & (HDIM - 1);
    const size_t r0 = (size_t)(1 + 4 * q) * HDIM + c; // W row 1+4q, own column
    uint4 z;
    z.x = f2h2(Wz[r0],            Wz[r0 + HDIM]);
    z.y = f2h2(Wr[r0],            Wr[r0 + HDIM]);
    z.z = f2h2(Wz[r0 + 2 * HDIM], Wz[r0 + 3 * HDIM]);
    z.w = f2h2(Wr[r0 + 2 * HDIM], Wr[r0 + 3 * HDIM]);
    ZR[idx] = z;
    uint2 h;
    h.x = f2h2(Wh[r0],            Wh[r0 + HDIM]);
    h.y = f2h2(Wh[r0 + 2 * HDIM], Wh[r0 + 3 * HDIM]);
    WH[idx] = h;
}

// One block per batch, 1024 threads (16 waves/CU). Thread (half, c) owns
// k-rows [half*256, half*256+256) of column c. All state block-local.
// Matvecs run entirely on v_dot2_f32_f16: fp16 weights (L2-streamed) x fp16
// h/hr (LDS) with fp32 accumulation. h itself is carried in fp32 registers;
// only the dot-product operand copy is rounded (same noise scale as the fp16
// weight rounding, which moved absmax by zero).
__launch_bounds__(1024, 4)
__global__ void mc_gru_k2_dot2_kernel(
    const float* __restrict__ inputs,  // (B, T)  [IN==1]
    const float* __restrict__ St,      // (B)
    const float* __restrict__ Mass,    // (B)
    const float* __restrict__ Wz,      // (513, 512) fp32 (row0 + scalars only)
    const float* __restrict__ bz,      // (512)
    const float* __restrict__ Wr,      // (513, 512)
    const float* __restrict__ br,      // (512)
    const float* __restrict__ Wh,      // (515, 512)
    const float* __restrict__ bh,      // (512)
    const float* __restrict__ Wk,      // (513)
    const float* __restrict__ bk,      // (1)
    const uint4* __restrict__ ZR,      // packed fp16 Wz|Wr
    const uint2* __restrict__ WH,      // packed fp16 Wh
    float* __restrict__ out)           // (B, T, H)
{
    __shared__ float x_l[TLEN];        // input row (4 KB)
    __shared__ uint2 h2_l[HDIM / 4];   // h_{t-1} as fp16 pairs (1 KB)
    __shared__ uint2 hr2_l[HDIM / 4];  // h*r as fp16 pairs (1 KB)
    __shared__ float az_s[2 * HDIM];   // per-(half,col) partials
    __shared__ float ar_s[2 * HDIM];
    __shared__ float ah_s[2 * HDIM];
    __shared__ float kw_l[8];          // per-wave partials of h_new . Wk

    const int tid  = threadIdx.x;
    const int b    = blockIdx.x;
    const int c    = tid & (HDIM - 1); // column 0..511
    const int half = tid >> 9;         // k-half 0/1 (wave-uniform)
    const int h2b  = half * (HALF / 4);// uint2 base index of own k-half

    for (int idx = tid; idx < TLEN; idx += 1024) x_l[idx] = inputs[b * TLEN + idx];
    if (tid < HDIM / 2) ((unsigned int*)h2_l)[tid] = 0u;   // h0 = 0

    // time-invariant per-column scalars (fp32 originals)
    const float wz0   = Wz[c];
    const float wr0   = Wr[c];
    const float wh0   = Wh[c];
    const float wh513 = Wh[513 * HDIM + c];
    const float wh514 = Wh[514 * HDIM + c];
    const float bzc   = bz[c];
    const float brc   = br[c];
    const float bhc   = bh[c];
    const float wkc   = Wk[c];
    const float wk512 = Wk[512];
    const float bk0   = bk[0];
    const float st    = St[b];
    const float mass  = Mass[b];

    // packed-weight bases: own column, own k-half (q = half*64 + qi)
    const uint4* __restrict__ zrp = ZR + (size_t)(half * 64) * HDIM + c;
    const uint2* __restrict__ whp = WH + (size_t)(half * 64) * HDIM + c;

    float h_reg = 0.0f;                // own h element (half-0 threads only)
    float k_reg = 0.0f;                // k carry (uniform)
    __syncthreads();

    for (int t = 0; t < TLEN; ++t) {
        const float x = x_l[t];

        // ---------- phase A: az/ar partial over own k-half (pure dot2) ----------
        float azp = 0.0f, arp = 0.0f;
        #pragma unroll 8
        for (int qi = 0; qi < HALF / 4; ++qi) {
            const uint4 v  = zrp[(size_t)qi * HDIM];   // 4 k-rows, both gates
            const uint2 hh = h2_l[h2b + qi];           // 4 h values (broadcast)
            azp = fdot2f(hh.x, v.x, azp);
            azp = fdot2f(hh.y, v.z, azp);
            arp = fdot2f(hh.x, v.y, arp);
            arp = fdot2f(hh.y, v.w, arp);
        }
        az_s[tid] = azp;
        ar_s[tid] = arp;
        __syncthreads();                           // S1: partials ready

        float z = 0.0f;
        if (half == 0) {                           // gates: half 0 only
            z = 1.0f / (1.0f + __expf(-(az_s[c] + az_s[HDIM + c] + x * wz0 + bzc)));
            const float r =
                1.0f / (1.0f + __expf(-(ar_s[c] + ar_s[HDIM + c] + x * wr0 + brc)));
            const float hr  = h_reg * r;
            const float hrn = __shfl_xor(hr, 1);
            if (!(c & 1)) ((unsigned int*)hr2_l)[c >> 1] = pack2(hr, hrn);
        }
        __syncthreads();                           // S2: hr2 ready

        // ---------- phase B: ah partial over own k-half ----------
        float ahp = 0.0f;
        #pragma unroll 8
        for (int qi = 0; qi < HALF / 4; ++qi) {
            const uint2 v  = whp[(size_t)qi * HDIM];
            const uint2 hh = hr2_l[h2b + qi];
            ahp = fdot2f(hh.x, v.x, ahp);
            ahp = fdot2f(hh.y, v.y, ahp);
        }
        ah_s[tid] = ahp;
        __syncthreads();                           // S3: ah partials ready

        if (half == 0) {                           // state update: half 0 only
            const float pre = ah_s[c] + ah_s[HDIM + c] + x * wh0
                            + (st * k_reg) * wh513 + mass * wh514 + bhc;
            const float e  = __expf(-2.0f * pre);
            const float ht = (1.0f - e) / (1.0f + e);  // tanh
            const float hn = (1.0f - z) * h_reg + z * ht;
            h_reg = hn;

            __builtin_nontemporal_store(hn, &out[((size_t)b * TLEN + t) * HDIM + c]);
            const float hnn = __shfl_xor(hn, 1);
            if (!(c & 1)) ((unsigned int*)h2_l)[c >> 1] = pack2(hn, hnn);

            float kc = hn * wkc;                   // h_new . Wk partial
            kc += __shfl_xor(kc, 1);
            kc += __shfl_xor(kc, 2);
            kc += __shfl_xor(kc, 4);
            kc += __shfl_xor(kc, 8);
            kc += __shfl_xor(kc, 16);
            kc += __shfl_xor(kc, 32);
            if ((tid & 63) == 0) kw_l[tid >> 6] = kc;
        }
        __syncthreads();                           // S4: h2 + kw published

        const float ksum = kw_l[0] + kw_l[1] + kw_l[2] + kw_l[3]
                         + kw_l[4] + kw_l[5] + kw_l[6] + kw_l[7];
        k_reg = 1.0f / (1.0f + __expf(-(ksum + wk512 * k_reg + bk0)));
    }
}

// ---------------- fallback: fp32 kernel (workspace too small) ----------------
__launch_bounds__(1024, 4)
__global__ void mc_gru_k2_kernel(
    const float* __restrict__ inputs, const float* __restrict__ St,
    const float* __restrict__ Mass, const float* __restrict__ Wz,
    const float* __restrict__ bz, const float* __restrict__ Wr,
    const float* __restrict__ br, const float* __restrict__ Wh,
    const float* __restrict__ bh, const float* __restrict__ Wk,
    const float* __restrict__ bk, float* __restrict__ out)
{
    __shared__ float x_l[TLEN];
    __shared__ float h_l[HDIM];
    __shared__ float hr_l[HDIM];
    __shared__ float az_s[2 * HDIM];
    __shared__ float ar_s[2 * HDIM];
    __shared__ float ah_s[2 * HDIM];
    __shared__ float kw_l[8];

    const int tid  = threadIdx.x;
    const int b    = blockIdx.x;
    const int c    = tid & (HDIM - 1);
    const int half = tid >> 9;
    const int klo  = half * HALF;

    for (int idx = tid; idx < TLEN; idx += 1024) x_l[idx] = inputs[b * TLEN + idx];
    if (tid < HDIM) h_l[tid] = 0.0f;

    const float wz0 = Wz[c], wr0 = Wr[c], wh0 = Wh[c];
    const float wh513 = Wh[513 * HDIM + c], wh514 = Wh[514 * HDIM + c];
    const float bzc = bz[c], brc = br[c], bhc = bh[c], wkc = Wk[c];
    const float wk512 = Wk[512], bk0 = bk[0];
    const float st = St[b], mass = Mass[b];

    const float* __restrict__ WzH = Wz + (size_t)(1 + klo) * HDIM + c;
    const float* __restrict__ WrH = Wr + (size_t)(1 + klo) * HDIM + c;
    const float* __restrict__ WhH = Wh + (size_t)(1 + klo) * HDIM + c;

    float k_reg = 0.0f;
    __syncthreads();

    for (int t = 0; t < TLEN; ++t) {
        const float x = x_l[t];
        float azp = 0.0f, arp = 0.0f;
        {
            const float4* h4 = (const float4*)&h_l[klo];
            #pragma unroll 4
            for (int kq = 0; kq < HALF / 4; ++kq) {
                const float4 hv = h4[kq];
                const int k = 4 * kq;
                azp += hv.x * WzH[(k + 0) * HDIM] + hv.y * WzH[(k + 1) * HDIM]
                     + hv.z * WzH[(k + 2) * HDIM] + hv.w * WzH[(k + 3) * HDIM];
                arp += hv.x * WrH[(k + 0) * HDIM] + hv.y * WrH[(k + 1) * HDIM]
                     + hv.z * WrH[(k + 2) * HDIM] + hv.w * WrH[(k + 3) * HDIM];
            }
        }
        az_s[tid] = azp;
        ar_s[tid] = arp;
        __syncthreads();

        const float z = 1.0f / (1.0f + __expf(-(az_s[c] + az_s[HDIM + c] + x * wz0 + bzc)));
        const float r = 1.0f / (1.0f + __expf(-(ar_s[c] + ar_s[HDIM + c] + x * wr0 + brc)));
        const float hvv = h_l[c];
        if (half == 0) hr_l[c] = hvv * r;
        __syncthreads();

        float ahp = 0.0f;
        {
            const float4* hr4 = (const float4*)&hr_l[klo];
            #pragma unroll 4
            for (int kq = 0; kq < HALF / 4; ++kq) {
                const float4 hv = hr4[kq];
                const int k = 4 * kq;
                ahp += hv.x * WhH[(k + 0) * HDIM] + hv.y * WhH[(k + 1) * HDIM]
                     + hv.z * WhH[(k + 2) * HDIM] + hv.w * WhH[(k + 3) * HDIM];
            }
        }
        ah_s[tid] = ahp;
        __syncthreads();

        const float pre = ah_s[c] + ah_s[HDIM + c] + x * wh0
                        + (st * k_reg) * wh513 + mass * wh514 + bhc;
        const float e  = __expf(-2.0f * pre);
        const float ht = (1.0f - e) / (1.0f + e);
        const float hn = (1.0f - z) * hvv + z * ht;

        if (half == 0) {
            __builtin_nontemporal_store(hn, &out[((size_t)b * TLEN + t) * HDIM + c]);
            h_l[c] = hn;
            float kc = hn * wkc;
            kc += __shfl_xor(kc, 1);
            kc += __shfl_xor(kc, 2);
            kc += __shfl_xor(kc, 4);
            kc += __shfl_xor(kc, 8);
            kc += __shfl_xor(kc, 16);
            kc += __shfl_xor(kc, 32);
            if ((tid & 63) == 0) kw_l[tid >> 6] = kc;
        }
        __syncthreads();

        const float ksum = kw_l[0] + kw_l[1] + kw_l[2] + kw_l[3]
                         + kw_l[4] + kw_l[5] + kw_l[6] + kw_l[7];
        k_reg = 1.0f / (1.0f + __expf(-(ksum + wk512 * k_reg + bk0)));
    }
}

extern "C" void kernel_launch(void* const* d_in, const int* in_sizes, int n_in,
                              void* d_out, int out_size, void* d_ws, size_t ws_size,
                              hipStream_t stream) {
    (void)in_sizes; (void)n_in; (void)out_size;

    const float* inputs = (const float*)d_in[0];
    const float* St     = (const float*)d_in[1];
    const float* Mass   = (const float*)d_in[2];
    const float* Wz     = (const float*)d_in[3];
    const float* bz     = (const float*)d_in[4];
    const float* Wr     = (const float*)d_in[5];
    const float* br     = (const float*)d_in[6];
    const float* Wh     = (const float*)d_in[7];
    const float* bh     = (const float*)d_in[8];
    const float* Wk     = (const float*)d_in[9];
    const float* bk     = (const float*)d_in[10];
    float* out = (float*)d_out;

    if (ws_size >= WS16_BYTES) {
        uint4* ZR = (uint4*)d_ws;
        uint2* WH = (uint2*)((char*)d_ws + WH_OFF_B);
        hipLaunchKernelGGL(convert_weights_kernel, dim3(ZR_ELEMS / 256), dim3(256),
                           0, stream, Wz, Wr, Wh, ZR, WH);
        hipLaunchKernelGGL(mc_gru_k2_dot2_kernel, dim3(BATCH), dim3(1024), 0, stream,
                           inputs, St, Mass, Wz, bz, Wr, br, Wh, bh, Wk, bk,
                           (const uint4*)ZR, (const uint2*)WH, out);
    } else {
        hipLaunchKernelGGL(mc_gru_k2_kernel, dim3(BATCH), dim3(1024), 0, stream,
                           inputs, St, Mass, Wz, bz, Wr, br, Wh, bh, Wk, bk, out);
    }
}

// Round 7
// 12967.546 us; speedup vs baseline: 3.1020x; 1.2488x over previous
//
#include <hip/hip_runtime.h>
#include <hip/hip_fp16.h>

// Problem constants (fixed by the reference)
#define BATCH 256
#define TLEN  1000
#define HDIM  512
#define HALF  256   // k-rows per half (2-way in-block k-split)
#define NQ    128   // 4-row k-groups (512/4)

// Residency split (per-half iteration space qi = 0..63, 4 k-rows each):
//   ZR: qi 0..5   in VGPRs (24 regs), qi 6..63 streamed from L2
//   WH: qi 0..19  in VGPRs (40 regs), qi 20..35 in LDS (128 KB), 36..63 streamed
#define ZR_REG   6
#define WH_REG   20
#define WH_LDS   16   // iters 20..35
#define WH_LDS_LO (WH_REG)
#define WH_STREAM_LO (WH_REG + WH_LDS)

// Packed fp16 weight workspace layout (in d_ws):
//   ZR[q][c] uint4: {h2(Wz r,r+1), h2(Wr r,r+1), h2(Wz r+2,r+3), h2(Wr r+2,r+3)}, r=1+4q
//   WH[q][c] uint2: {h2(Wh r,r+1), h2(Wh r+2,r+3)}
#define ZR_ELEMS   (NQ * HDIM)                       // 65536 uint4 = 1 MB
#define WH_OFF_B   ((size_t)ZR_ELEMS * 16)
#define WS16_BYTES (WH_OFF_B + (size_t)ZR_ELEMS * 8) // 1.573 MB

typedef _Float16 f16;
typedef f16 f16x2 __attribute__((ext_vector_type(2)));

__device__ __forceinline__ unsigned int f2h2(float a, float b) {
    __half2 h = __halves2half2(__float2half_rn(a), __float2half_rn(b));
    return __builtin_bit_cast(unsigned int, h);
}

// fp16x2 dot with fp32 accumulate: v_dot2_f32_f16 (one instr, no cvts)
__device__ __forceinline__ float fdot2f(unsigned int a, unsigned int b, float c) {
#if __has_builtin(__builtin_amdgcn_fdot2)
    return __builtin_amdgcn_fdot2(__builtin_bit_cast(f16x2, a),
                                  __builtin_bit_cast(f16x2, b), c, false);
#else
    const f16x2 x = __builtin_bit_cast(f16x2, a);
    const f16x2 y = __builtin_bit_cast(f16x2, b);
    return c + (float)x[0] * (float)y[0] + (float)x[1] * (float)y[1];
#endif
}

// pack two fp32 -> fp16x2 (single v_cvt_pkrtz_f16_f32 where available)
__device__ __forceinline__ unsigned int pack2(float a, float b) {
#if __has_builtin(__builtin_amdgcn_cvt_pkrtz)
    return __builtin_bit_cast(unsigned int, __builtin_amdgcn_cvt_pkrtz(a, b));
#else
    f16x2 v; v[0] = (f16)a; v[1] = (f16)b;
    return __builtin_bit_cast(unsigned int, v);
#endif
}

// per-launch weight conversion (d_ws is poisoned before every launch)
__global__ void convert_weights_kernel(
    const float* __restrict__ Wz, const float* __restrict__ Wr,
    const float* __restrict__ Wh, uint4* __restrict__ ZR, uint2* __restrict__ WH)
{
    const int idx = blockIdx.x * 256 + threadIdx.x;   // 0..65535
    const int q = idx >> 9;                           // 0..127
    const int c = idx & (HDIM - 1);
    const size_t r0 = (size_t)(1 + 4 * q) * HDIM + c; // W row 1+4q, own column
    uint4 z;
    z.x = f2h2(Wz[r0],            Wz[r0 + HDIM]);
    z.y = f2h2(Wr[r0],            Wr[r0 + HDIM]);
    z.z = f2h2(Wz[r0 + 2 * HDIM], Wz[r0 + 3 * HDIM]);
    z.w = f2h2(Wr[r0 + 2 * HDIM], Wr[r0 + 3 * HDIM]);
    ZR[idx] = z;
    uint2 h;
    h.x = f2h2(Wh[r0],            Wh[r0 + HDIM]);
    h.y = f2h2(Wh[r0 + 2 * HDIM], Wh[r0 + 3 * HDIM]);
    WH[idx] = h;
}

// One block per batch, 1024 threads (16 waves/CU). Thread (half, c) owns
// k-rows [half*256, half*256+256) of column c. All state block-local.
// The fp16 weight stream runs at the device L2 roofline (~36 TB/s aggregate),
// so this round parks time-invariant weight chunks in idle on-CU storage
// (VGPRs + 128 KB LDS) at t=0: streamed bytes/CU/step 1.536 -> 1.152 MB.
__launch_bounds__(1024, 4)
__global__ void mc_gru_k2_res_kernel(
    const float* __restrict__ inputs,  // (B, T)  [IN==1]
    const float* __restrict__ St,      // (B)
    const float* __restrict__ Mass,    // (B)
    const float* __restrict__ Wz,      // (513, 512) fp32 (row0 + scalars only)
    const float* __restrict__ bz,      // (512)
    const float* __restrict__ Wr,      // (513, 512)
    const float* __restrict__ br,      // (512)
    const float* __restrict__ Wh,      // (515, 512)
    const float* __restrict__ bh,      // (512)
    const float* __restrict__ Wk,      // (513)
    const float* __restrict__ bk,      // (1)
    const uint4* __restrict__ ZR,      // packed fp16 Wz|Wr
    const uint2* __restrict__ WH,      // packed fp16 Wh
    float* __restrict__ out)           // (B, T, H)
{
    __shared__ float x_l[TLEN];          // input row (4 KB)
    __shared__ uint2 h2_l[HDIM / 4];     // h_{t-1} as fp16 pairs (1 KB)
    __shared__ uint2 hr2_l[HDIM / 4];    // h*r as fp16 pairs (1 KB)
    __shared__ float az_s[2 * HDIM];     // per-(half,col) partials (4 KB each)
    __shared__ float ar_s[2 * HDIM];
    __shared__ float ah_s[2 * HDIM];
    __shared__ float kw_l[8];
    __shared__ uint2 whl[WH_LDS][1024];  // LDS-resident WH iters 20..35 (128 KB)

    const int tid  = threadIdx.x;
    const int b    = blockIdx.x;
    const int c    = tid & (HDIM - 1); // column 0..511
    const int half = tid >> 9;         // k-half 0/1 (wave-uniform)
    const int h2b  = half * (HALF / 4);// uint2 base index of own k-half

    for (int idx = tid; idx < TLEN; idx += 1024) x_l[idx] = inputs[b * TLEN + idx];
    if (tid < HDIM / 2) ((unsigned int*)h2_l)[tid] = 0u;   // h0 = 0

    // time-invariant per-column scalars (fp32 originals)
    const float wz0   = Wz[c];
    const float wr0   = Wr[c];
    const float wh0   = Wh[c];
    const float wh513 = Wh[513 * HDIM + c];
    const float wh514 = Wh[514 * HDIM + c];
    const float bzc   = bz[c];
    const float brc   = br[c];
    const float bhc   = bh[c];
    const float wkc   = Wk[c];
    const float wk512 = Wk[512];
    const float bk0   = bk[0];
    const float st    = St[b];
    const float mass  = Mass[b];

    // packed-weight bases: own column, own k-half (q = half*64 + qi)
    const uint4* __restrict__ zrp = ZR + (size_t)(half * 64) * HDIM + c;
    const uint2* __restrict__ whp = WH + (size_t)(half * 64) * HDIM + c;

    // ---- one-time weight residency (read-only for the whole kernel) ----
    uint4 zr_r[ZR_REG];
    #pragma unroll
    for (int qi = 0; qi < ZR_REG; ++qi) zr_r[qi] = zrp[(size_t)qi * HDIM];
    uint2 wh_r[WH_REG];
    #pragma unroll
    for (int qi = 0; qi < WH_REG; ++qi) wh_r[qi] = whp[(size_t)qi * HDIM];
    #pragma unroll
    for (int i = 0; i < WH_LDS; ++i)
        whl[i][tid] = whp[(size_t)(WH_LDS_LO + i) * HDIM];

    float h_reg = 0.0f;                // own h element (half-0 threads only)
    float k_reg = 0.0f;                // k carry (uniform)
    __syncthreads();

    for (int t = 0; t < TLEN; ++t) {
        const float x = x_l[t];

        // ---------- phase A: az/ar partial over own k-half ----------
        float azp = 0.0f, arp = 0.0f;
        #pragma unroll
        for (int qi = 0; qi < ZR_REG; ++qi) {      // register-resident
            const uint4 v  = zr_r[qi];
            const uint2 hh = h2_l[h2b + qi];
            azp = fdot2f(hh.x, v.x, azp);
            azp = fdot2f(hh.y, v.z, azp);
            arp = fdot2f(hh.x, v.y, arp);
            arp = fdot2f(hh.y, v.w, arp);
        }
        #pragma unroll 8
        for (int qi = ZR_REG; qi < HALF / 4; ++qi) { // L2-streamed
            const uint4 v  = zrp[(size_t)qi * HDIM];
            const uint2 hh = h2_l[h2b + qi];
            azp = fdot2f(hh.x, v.x, azp);
            azp = fdot2f(hh.y, v.z, azp);
            arp = fdot2f(hh.x, v.y, arp);
            arp = fdot2f(hh.y, v.w, arp);
        }
        az_s[tid] = azp;
        ar_s[tid] = arp;
        __syncthreads();                           // S1: partials ready

        float z = 0.0f;
        if (half == 0) {                           // gates: half 0 only
            z = 1.0f / (1.0f + __expf(-(az_s[c] + az_s[HDIM + c] + x * wz0 + bzc)));
            const float r =
                1.0f / (1.0f + __expf(-(ar_s[c] + ar_s[HDIM + c] + x * wr0 + brc)));
            const float hr  = h_reg * r;
            const float hrn = __shfl_xor(hr, 1);
            if (!(c & 1)) ((unsigned int*)hr2_l)[c >> 1] = pack2(hr, hrn);
        }
        __syncthreads();                           // S2: hr2 ready

        // ---------- phase B: ah partial over own k-half ----------
        float ahp = 0.0f;
        #pragma unroll 7
        for (int qi = WH_STREAM_LO; qi < HALF / 4; ++qi) { // streamed (issue early)
            const uint2 v  = whp[(size_t)qi * HDIM];
            const uint2 hh = hr2_l[h2b + qi];
            ahp = fdot2f(hh.x, v.x, ahp);
            ahp = fdot2f(hh.y, v.y, ahp);
        }
        #pragma unroll
        for (int qi = 0; qi < WH_REG; ++qi) {      // register-resident
            const uint2 v  = wh_r[qi];
            const uint2 hh = hr2_l[h2b + qi];
            ahp = fdot2f(hh.x, v.x, ahp);
            ahp = fdot2f(hh.y, v.y, ahp);
        }
        #pragma unroll
        for (int i = 0; i < WH_LDS; ++i) {         // LDS-resident
            const uint2 v  = whl[i][tid];
            const uint2 hh = hr2_l[h2b + WH_LDS_LO + i];
            ahp = fdot2f(hh.x, v.x, ahp);
            ahp = fdot2f(hh.y, v.y, ahp);
        }
        ah_s[tid] = ahp;
        __syncthreads();                           // S3: ah partials ready

        if (half == 0) {                           // state update: half 0 only
            const float pre = ah_s[c] + ah_s[HDIM + c] + x * wh0
                            + (st * k_reg) * wh513 + mass * wh514 + bhc;
            const float e  = __expf(-2.0f * pre);
            const float ht = (1.0f - e) / (1.0f + e);  // tanh
            const float hn = (1.0f - z) * h_reg + z * ht;
            h_reg = hn;

            __builtin_nontemporal_store(hn, &out[((size_t)b * TLEN + t) * HDIM + c]);
            const float hnn = __shfl_xor(hn, 1);
            if (!(c & 1)) ((unsigned int*)h2_l)[c >> 1] = pack2(hn, hnn);

            float kc = hn * wkc;                   // h_new . Wk partial
            kc += __shfl_xor(kc, 1);
            kc += __shfl_xor(kc, 2);
            kc += __shfl_xor(kc, 4);
            kc += __shfl_xor(kc, 8);
            kc += __shfl_xor(kc, 16);
            kc += __shfl_xor(kc, 32);
            if ((tid & 63) == 0) kw_l[tid >> 6] = kc;
        }
        __syncthreads();                           // S4: h2 + kw published

        const float ksum = kw_l[0] + kw_l[1] + kw_l[2] + kw_l[3]
                         + kw_l[4] + kw_l[5] + kw_l[6] + kw_l[7];
        k_reg = 1.0f / (1.0f + __expf(-(ksum + wk512 * k_reg + bk0)));
    }
}

// ---------------- fallback: fp32 kernel (workspace too small) ----------------
__launch_bounds__(1024, 4)
__global__ void mc_gru_k2_kernel(
    const float* __restrict__ inputs, const float* __restrict__ St,
    const float* __restrict__ Mass, const float* __restrict__ Wz,
    const float* __restrict__ bz, const float* __restrict__ Wr,
    const float* __restrict__ br, const float* __restrict__ Wh,
    const float* __restrict__ bh, const float* __restrict__ Wk,
    const float* __restrict__ bk, float* __restrict__ out)
{
    __shared__ float x_l[TLEN];
    __shared__ float h_l[HDIM];
    __shared__ float hr_l[HDIM];
    __shared__ float az_s[2 * HDIM];
    __shared__ float ar_s[2 * HDIM];
    __shared__ float ah_s[2 * HDIM];
    __shared__ float kw_l[8];

    const int tid  = threadIdx.x;
    const int b    = blockIdx.x;
    const int c    = tid & (HDIM - 1);
    const int half = tid >> 9;
    const int klo  = half * HALF;

    for (int idx = tid; idx < TLEN; idx += 1024) x_l[idx] = inputs[b * TLEN + idx];
    if (tid < HDIM) h_l[tid] = 0.0f;

    const float wz0 = Wz[c], wr0 = Wr[c], wh0 = Wh[c];
    const float wh513 = Wh[513 * HDIM + c], wh514 = Wh[514 * HDIM + c];
    const float bzc = bz[c], brc = br[c], bhc = bh[c], wkc = Wk[c];
    const float wk512 = Wk[512], bk0 = bk[0];
    const float st = St[b], mass = Mass[b];

    const float* __restrict__ WzH = Wz + (size_t)(1 + klo) * HDIM + c;
    const float* __restrict__ WrH = Wr + (size_t)(1 + klo) * HDIM + c;
    const float* __restrict__ WhH = Wh + (size_t)(1 + klo) * HDIM + c;

    float k_reg = 0.0f;
    __syncthreads();

    for (int t = 0; t < TLEN; ++t) {
        const float x = x_l[t];
        float azp = 0.0f, arp = 0.0f;
        {
            const float4* h4 = (const float4*)&h_l[klo];
            #pragma unroll 4
            for (int kq = 0; kq < HALF / 4; ++kq) {
                const float4 hv = h4[kq];
                const int k = 4 * kq;
                azp += hv.x * WzH[(k + 0) * HDIM] + hv.y * WzH[(k + 1) * HDIM]
                     + hv.z * WzH[(k + 2) * HDIM] + hv.w * WzH[(k + 3) * HDIM];
                arp += hv.x * WrH[(k + 0) * HDIM] + hv.y * WrH[(k + 1) * HDIM]
                     + hv.z * WrH[(k + 2) * HDIM] + hv.w * WrH[(k + 3) * HDIM];
            }
        }
        az_s[tid] = azp;
        ar_s[tid] = arp;
        __syncthreads();

        const float z = 1.0f / (1.0f + __expf(-(az_s[c] + az_s[HDIM + c] + x * wz0 + bzc)));
        const float r = 1.0f / (1.0f + __expf(-(ar_s[c] + ar_s[HDIM + c] + x * wr0 + brc)));
        const float hvv = h_l[c];
        if (half == 0) hr_l[c] = hvv * r;
        __syncthreads();

        float ahp = 0.0f;
        {
            const float4* hr4 = (const float4*)&hr_l[klo];
            #pragma unroll 4
            for (int kq = 0; kq < HALF / 4; ++kq) {
                const float4 hv = hr4[kq];
                const int k = 4 * kq;
                ahp += hv.x * WhH[(k + 0) * HDIM] + hv.y * WhH[(k + 1) * HDIM]
                     + hv.z * WhH[(k + 2) * HDIM] + hv.w * WhH[(k + 3) * HDIM];
            }
        }
        ah_s[tid] = ahp;
        __syncthreads();

        const float pre = ah_s[c] + ah_s[HDIM + c] + x * wh0
                        + (st * k_reg) * wh513 + mass * wh514 + bhc;
        const float e  = __expf(-2.0f * ah_s[c] * 0.0f - 2.0f * pre); // keep form
        const float ht = (1.0f - e) / (1.0f + e);
        const float hn = (1.0f - z) * hvv + z * ht;

        if (half == 0) {
            __builtin_nontemporal_store(hn, &out[((size_t)b * TLEN + t) * HDIM + c]);
            h_l[c] = hn;
            float kc = hn * wkc;
            kc += __shfl_xor(kc, 1);
            kc += __shfl_xor(kc, 2);
            kc += __shfl_xor(kc, 4);
            kc += __shfl_xor(kc, 8);
            kc += __shfl_xor(kc, 16);
            kc += __shfl_xor(kc, 32);
            if ((tid & 63) == 0) kw_l[tid >> 6] = kc;
        }
        __syncthreads();

        const float ksum = kw_l[0] + kw_l[1] + kw_l[2] + kw_l[3]
                         + kw_l[4] + kw_l[5] + kw_l[6] + kw_l[7];
        k_reg = 1.0f / (1.0f + __expf(-(ksum + wk512 * k_reg + bk0)));
    }
}

extern "C" void kernel_launch(void* const* d_in, const int* in_sizes, int n_in,
                              void* d_out, int out_size, void* d_ws, size_t ws_size,
                              hipStream_t stream) {
    (void)in_sizes; (void)n_in; (void)out_size;

    const float* inputs = (const float*)d_in[0];
    const float* St     = (const float*)d_in[1];
    const float* Mass   = (const float*)d_in[2];
    const float* Wz     = (const float*)d_in[3];
    const float* bz     = (const float*)d_in[4];
    const float* Wr     = (const float*)d_in[5];
    const float* br     = (const float*)d_in[6];
    const float* Wh     = (const float*)d_in[7];
    const float* bh     = (const float*)d_in[8];
    const float* Wk     = (const float*)d_in[9];
    const float* bk     = (const float*)d_in[10];
    float* out = (float*)d_out;

    if (ws_size >= WS16_BYTES) {
        uint4* ZR = (uint4*)d_ws;
        uint2* WH = (uint2*)((char*)d_ws + WH_OFF_B);
        hipLaunchKernelGGL(convert_weights_kernel, dim3(ZR_ELEMS / 256), dim3(256),
                           0, stream, Wz, Wr, Wh, ZR, WH);
        hipLaunchKernelGGL(mc_gru_k2_res_kernel, dim3(BATCH), dim3(1024), 0, stream,
                           inputs, St, Mass, Wz, bz, Wr, br, Wh, bh, Wk, bk,
                           (const uint4*)ZR, (const uint2*)WH, out);
    } else {
        hipLaunchKernelGGL(mc_gru_k2_kernel, dim3(BATCH), dim3(1024), 0, stream,
                           inputs, St, Mass, Wz, bz, Wr, br, Wh, bh, Wk, bk, out);
    }
}